// Round 2
// baseline (226.837 us; speedup 1.0000x reference)
//
#include <hip/hip_runtime.h>
#include <stdint.h>

typedef unsigned short u16;
typedef __bf16 bf16x8 __attribute__((ext_vector_type(8)));
typedef float f32x4 __attribute__((ext_vector_type(4)));

__device__ __forceinline__ float b2f(u16 u) {
  union { uint32_t i; float f; } x; x.i = ((uint32_t)u) << 16; return x.f;
}
__device__ __forceinline__ u16 f2b(float f) {
  union { float f; uint32_t i; } x; x.f = f;
  uint32_t r = x.i + 0x7fffu + ((x.i >> 16) & 1u);
  return (u16)(r >> 16);
}
// pack 8 fp32 -> 8 bf16 (RNE) as uint4
__device__ __forceinline__ uint4 pk8(const float4 a, const float4 b) {
  uint4 r;
  r.x = (uint32_t)f2b(a.x) | ((uint32_t)f2b(a.y) << 16);
  r.y = (uint32_t)f2b(a.z) | ((uint32_t)f2b(a.w) << 16);
  r.z = (uint32_t)f2b(b.x) | ((uint32_t)f2b(b.y) << 16);
  r.w = (uint32_t)f2b(b.z) | ((uint32_t)f2b(b.w) << 16);
  return r;
}

// ---------------------------------------------------------------------------
// GEMM: C[m,n] = sum_k A[m,k] * B[n,k]   (row-major, K contiguous)
// MODE 0: A fp32 (x), B fp32 (qkv_w)  -> scatter bf16 into [3][B][H][N][D] ws
// MODE 1: A bf16 (attn out ws), B fp32 (proj_w) -> fp32 out + fp32 bias
// 128x128 tile, BK=32, 4 waves (2x2 of 64x64), 16x16x32 bf16 MFMA.
// fp32 sides converted to bf16 at LDS-staging time.
// ---------------------------------------------------------------------------
template<int MODE>
__launch_bounds__(256)
__global__ void gemm128(const void* __restrict__ Ap, const float* __restrict__ Bw,
                        void* __restrict__ Cp, const float* __restrict__ bias, int K) {
  __shared__ __align__(16) u16 As[128 * 32];
  __shared__ __align__(16) u16 Bs[128 * 32];
  const int t = threadIdx.x;
  const int w = t >> 6, l = t & 63, lr = l & 15, lg = l >> 4;
  const int m0 = blockIdx.y * 128, n0 = blockIdx.x * 128;
  const int wm = (w >> 1) * 64, wn = (w & 1) * 64;
  const int srow = t >> 2, scol = (t & 3) * 8;

  const float* gB = Bw + (n0 + srow) * K + scol;
  float4 fb0a = *(const float4*)(gB);
  float4 fb0b = *(const float4*)(gB + 4);
  float4 fb1a = *(const float4*)(gB + 64 * K);
  float4 fb1b = *(const float4*)(gB + 64 * K + 4);

  const float* gAf = (const float*)Ap + (m0 + srow) * K + scol;
  const u16*  gAh = (const u16*)Ap + (m0 + srow) * K + scol;
  float4 fa0a, fa0b, fa1a, fa1b;
  uint4 ha0, ha1;
  if (MODE == 0) {
    fa0a = *(const float4*)(gAf);
    fa0b = *(const float4*)(gAf + 4);
    fa1a = *(const float4*)(gAf + 64 * K);
    fa1b = *(const float4*)(gAf + 64 * K + 4);
  } else {
    ha0 = *(const uint4*)(gAh);
    ha1 = *(const uint4*)(gAh + 64 * K);
  }

  f32x4 acc[4][4] = {};
  const int nk = K >> 5;
  for (int kt = 0; kt < nk; ++kt) {
    __syncthreads();
    if (MODE == 0) {
      *(uint4*)(As + t * 8)        = pk8(fa0a, fa0b);
      *(uint4*)(As + t * 8 + 2048) = pk8(fa1a, fa1b);
    } else {
      *(uint4*)(As + t * 8)        = ha0;
      *(uint4*)(As + t * 8 + 2048) = ha1;
    }
    *(uint4*)(Bs + t * 8)        = pk8(fb0a, fb0b);
    *(uint4*)(Bs + t * 8 + 2048) = pk8(fb1a, fb1b);
    __syncthreads();
    if (kt + 1 < nk) {
      const int o = (kt + 1) * 32;
      if (MODE == 0) {
        fa0a = *(const float4*)(gAf + o);
        fa0b = *(const float4*)(gAf + o + 4);
        fa1a = *(const float4*)(gAf + o + 64 * K);
        fa1b = *(const float4*)(gAf + o + 64 * K + 4);
      } else {
        ha0 = *(const uint4*)(gAh + o);
        ha1 = *(const uint4*)(gAh + o + 64 * K);
      }
      fb0a = *(const float4*)(gB + o);
      fb0b = *(const float4*)(gB + o + 4);
      fb1a = *(const float4*)(gB + o + 64 * K);
      fb1b = *(const float4*)(gB + o + 64 * K + 4);
    }
    bf16x8 af[4], bfr[4];
#pragma unroll
    for (int i = 0; i < 4; ++i)
      af[i] = *(const bf16x8*)(As + (wm + i * 16 + lr) * 32 + lg * 8);
#pragma unroll
    for (int j = 0; j < 4; ++j)
      bfr[j] = *(const bf16x8*)(Bs + (wn + j * 16 + lr) * 32 + lg * 8);
#pragma unroll
    for (int i = 0; i < 4; ++i)
#pragma unroll
      for (int j = 0; j < 4; ++j)
        acc[i][j] = __builtin_amdgcn_mfma_f32_16x16x32_bf16(af[i], bfr[j], acc[i][j], 0, 0, 0);
  }
  // epilogue: C/D layout col=lane&15, row=(lane>>4)*4+reg
#pragma unroll
  for (int i = 0; i < 4; ++i)
#pragma unroll
    for (int j = 0; j < 4; ++j)
#pragma unroll
      for (int r = 0; r < 4; ++r) {
        const int gm = m0 + wm + i * 16 + lg * 4 + r;
        const int gn = n0 + wn + j * 16 + lr;
        const float v = acc[i][j][r];
        if (MODE == 0) {
          const int which = gn >> 10, hh = (gn >> 6) & 15, dd = gn & 63;
          const int bb = gm >> 10, pp = gm & 1023;
          ((u16*)Cp)[which * 4194304 + ((bb * 16 + hh) << 16) + (pp << 6) + dd] = f2b(v);
        } else {
          ((float*)Cp)[(gm << 10) + gn] = v + bias[gn];
        }
      }
}

// ---------------------------------------------------------------------------
// LayerNorm(D=64) + RoPE over q and k regions (131072 rows of 64), in place
// on bf16 ws. One wave handles 2 rows: 32 lanes/row, 2 elems/lane.
// ---------------------------------------------------------------------------
__launch_bounds__(256)
__global__ void ln_rope(u16* __restrict__ qk, const float* __restrict__ qn_w,
                        const float* __restrict__ qn_b, const float* __restrict__ kn_w,
                        const float* __restrict__ kn_b) {
  const int t = threadIdx.x;
  const int wid = blockIdx.x * 4 + (t >> 6);
  const int l = t & 63;
  const int row = wid * 2 + (l >> 5);
  const int j = l & 31, d0 = j * 2;
  const int which = row >> 16;   // 65536 rows per q/k region
  const int pos = row & 1023;
  const float* wgt = which ? kn_w : qn_w;
  const float* bia = which ? kn_b : qn_b;
  u16* p = qk + row * 64 + d0;
  const ushort2 raw = *(const ushort2*)p;
  float v0 = b2f(raw.x), v1 = b2f(raw.y);
  float s = v0 + v1;
#pragma unroll
  for (int off = 1; off < 32; off <<= 1) s += __shfl_xor(s, off);
  const float mu = s * 0.015625f;
  const float e0 = v0 - mu, e1 = v1 - mu;
  float qsum = e0 * e0 + e1 * e1;
#pragma unroll
  for (int off = 1; off < 32; off <<= 1) qsum += __shfl_xor(qsum, off);
  const float rstd = rsqrtf(qsum * 0.015625f + 1e-5f);
  const float n0 = e0 * rstd * wgt[d0] + bia[d0];
  const float n1 = e1 * rstd * wgt[d0 + 1] + bia[d0 + 1];
  // rotate_half partner lives at d ^ 32  -> lane ^ 16 within the 32-lane half
  const float p0 = __shfl_xor(n0, 16);
  const float p1 = __shfl_xor(n1, 16);
  const bool lo = (d0 < 32);
  const float r0 = lo ? -p0 : p0, r1 = lo ? -p1 : p1;
  const int dd0 = d0 & 31;
  const float cfac = -0.41524101186092029f; // -log2(10000)/32
  const float f0 = pos * exp2f(dd0 * cfac);
  const float f1 = pos * exp2f((dd0 + 1) * cfac);
  float s0, c0, s1, c1;
  sincosf(f0, &s0, &c0);
  sincosf(f1, &s1, &c1);
  ushort2 o;
  o.x = f2b(n0 * c0 + r0 * s0);
  o.y = f2b(n1 * c1 + r1 * s1);
  *(ushort2*)p = o;
}

// ---------------------------------------------------------------------------
// V transpose: [B,H,N,D] -> [B,H,D,N] via 128x64 LDS tile (bf16 ws).
// ---------------------------------------------------------------------------
__launch_bounds__(256)
__global__ void vtrans(const u16* __restrict__ v, u16* __restrict__ vt) {
  __shared__ u16 tile[128 * 65];
  const int t = threadIdx.x;
  const int bh = blockIdx.x >> 3;
  const int n0 = (blockIdx.x & 7) * 128;
  const u16* src = v + bh * 65536 + n0 * 64;
#pragma unroll
  for (int it = 0; it < 8; ++it) {
    const int e = (it * 256 + t) * 4;
    const int n = e >> 6, d = e & 63;
    const ushort4 x = *(const ushort4*)(src + n * 64 + d);
    tile[n * 65 + d + 0] = x.x;
    tile[n * 65 + d + 1] = x.y;
    tile[n * 65 + d + 2] = x.z;
    tile[n * 65 + d + 3] = x.w;
  }
  __syncthreads();
  u16* dst = vt + bh * 65536 + n0;
#pragma unroll
  for (int it = 0; it < 8; ++it) {
    const int o = (it * 256 + t) * 4;
    const int d = o >> 7, c = o & 127;
    ushort4 y;
    y.x = tile[(c + 0) * 65 + d];
    y.y = tile[(c + 1) * 65 + d];
    y.z = tile[(c + 2) * 65 + d];
    y.w = tile[(c + 3) * 65 + d];
    *(ushort4*)(dst + d * 1024 + c) = y;
  }
}

// ---------------------------------------------------------------------------
// Sliding-window attention with sinks. One wave per 16 q-rows.
// QK^T: 17 coltiles of 16 keys held in registers (17 x f32x4, C-layout).
// Softmax in registers (shfl over the 16-lane col group), P -> LDS (bf16,
// A-layout source), PV: 9 K-steps x 4 d-tiles, V^T frags direct from global.
// ---------------------------------------------------------------------------
__launch_bounds__(256)
__global__ void attn_kernel(const u16* __restrict__ q, const u16* __restrict__ k,
                            const u16* __restrict__ vt, const float* __restrict__ sinks,
                            u16* __restrict__ ao) {
  __shared__ __align__(16) u16 pbuf[4][16 * 296];
  const int t = threadIdx.x, w = t >> 6, l = t & 63, lr = l & 15, lg = l >> 4;
  const int bid = blockIdx.x;
  const int qb = bid & 15, h = (bid >> 4) & 15, b = bid >> 8;
  const int i0 = qb * 64 + w * 16;
  const int bh = b * 16 + h;
  const u16* qp = q + bh * 65536;
  const u16* kp = k + bh * 65536;
  const u16* vp = vt + bh * 65536;
  u16* pb = pbuf[w];

  const bf16x8 qf0 = *(const bf16x8*)(qp + (i0 + lr) * 64 + lg * 8);
  const bf16x8 qf1 = *(const bf16x8*)(qp + (i0 + lr) * 64 + 32 + lg * 8);
  const int ja = i0 - 256;

  f32x4 sacc[17];
#pragma unroll
  for (int jt = 0; jt < 17; ++jt) {
    const int jr = ja + jt * 16 + lr;
    const int jc = jr < 0 ? 0 : jr;
    const bf16x8 kf0 = *(const bf16x8*)(kp + jc * 64 + lg * 8);
    const bf16x8 kf1 = *(const bf16x8*)(kp + jc * 64 + 32 + lg * 8);
    f32x4 a = {0.f, 0.f, 0.f, 0.f};
    a = __builtin_amdgcn_mfma_f32_16x16x32_bf16(qf0, kf0, a, 0, 0, 0);
    a = __builtin_amdgcn_mfma_f32_16x16x32_bf16(qf1, kf1, a, 0, 0, 0);
    sacc[jt] = a;
  }
  const float sink = sinks[h];
  float mx[4] = {-1e30f, -1e30f, -1e30f, -1e30f};
#pragma unroll
  for (int jt = 0; jt < 17; ++jt)
#pragma unroll
    for (int r = 0; r < 4; ++r) {
      const int qi = i0 + lg * 4 + r;
      const int jg = ja + jt * 16 + lr;
      const bool ok = (jg >= 0) && (jg <= qi) && (jg > qi - 256);
      const float sv = ok ? sacc[jt][r] * 0.125f : -1e30f;
      sacc[jt][r] = sv;
      mx[r] = fmaxf(mx[r], sv);
    }
#pragma unroll
  for (int off = 1; off < 16; off <<= 1)
#pragma unroll
    for (int r = 0; r < 4; ++r) mx[r] = fmaxf(mx[r], __shfl_xor(mx[r], off));
#pragma unroll
  for (int r = 0; r < 4; ++r) mx[r] = fmaxf(mx[r], sink);
  float sum[4] = {0.f, 0.f, 0.f, 0.f};
#pragma unroll
  for (int jt = 0; jt < 17; ++jt)
#pragma unroll
    for (int r = 0; r < 4; ++r) {
      const float e = __expf(sacc[jt][r] - mx[r]);
      sacc[jt][r] = e;
      sum[r] += e;
    }
#pragma unroll
  for (int off = 1; off < 16; off <<= 1)
#pragma unroll
    for (int r = 0; r < 4; ++r) sum[r] += __shfl_xor(sum[r], off);
  float inv[4];
#pragma unroll
  for (int r = 0; r < 4; ++r) inv[r] = 1.0f / (sum[r] + __expf(sink - mx[r]));
  // zero pad cols [272,288) so the 9th PV K-step contributes nothing
  {
    ushort4 z; z.x = 0; z.y = 0; z.z = 0; z.w = 0;
    *(ushort4*)(pb + (l >> 2) * 296 + 272 + (l & 3) * 4) = z;
  }
#pragma unroll
  for (int jt = 0; jt < 17; ++jt)
#pragma unroll
    for (int r = 0; r < 4; ++r)
      pb[(lg * 4 + r) * 296 + jt * 16 + lr] = f2b(sacc[jt][r] * inv[r]);

  f32x4 oacc[4] = {};
#pragma unroll
  for (int ks = 0; ks < 9; ++ks) {
    const bf16x8 pf = *(const bf16x8*)(pb + lr * 296 + ks * 32 + lg * 8);
#pragma unroll
    for (int dt = 0; dt < 4; ++dt) {
      int jg = ja + ks * 32 + lg * 8;
      jg = jg < 0 ? 0 : (jg > 1016 ? 1016 : jg);
      const bf16x8 vf = *(const bf16x8*)(vp + (dt * 16 + lr) * 1024 + jg);
      oacc[dt] = __builtin_amdgcn_mfma_f32_16x16x32_bf16(pf, vf, oacc[dt], 0, 0, 0);
    }
  }
#pragma unroll
  for (int dt = 0; dt < 4; ++dt)
#pragma unroll
    for (int r = 0; r < 4; ++r) {
      const int m = (b << 10) + i0 + lg * 4 + r;
      ao[(m << 10) + (h << 6) + dt * 16 + lr] = f2b(oacc[dt][r]);
    }
}

// ---------------------------------------------------------------------------
// Launch: qkv GEMM -> LN+RoPE -> V transpose -> attention -> proj GEMM
// Workspace (bf16 elems): qkv [3][B][H][N][D] @0, vT @12582912, attn_out @16777216
// Total 41,943,040 bytes.
// ---------------------------------------------------------------------------
extern "C" void kernel_launch(void* const* d_in, const int* in_sizes, int n_in,
                              void* d_out, int out_size, void* d_ws, size_t ws_size,
                              hipStream_t stream) {
  const float* x      = (const float*)d_in[0];
  const float* qkv_w  = (const float*)d_in[1];
  const float* qn_w   = (const float*)d_in[2];
  const float* qn_b   = (const float*)d_in[3];
  const float* kn_w   = (const float*)d_in[4];
  const float* kn_b   = (const float*)d_in[5];
  const float* sinks  = (const float*)d_in[6];
  const float* proj_w = (const float*)d_in[7];
  const float* proj_b = (const float*)d_in[8];
  float* out = (float*)d_out;
  u16* ws  = (u16*)d_ws;
  u16* qkv = ws;                    // q @0, k @4194304, v @8388608
  u16* vtw = ws + 12582912;
  u16* ao  = ws + 16777216;

  gemm128<0><<<dim3(24, 32), 256, 0, stream>>>(x, qkv_w, qkv, nullptr, 1024);
  ln_rope<<<16384, 256, 0, stream>>>(qkv, qn_w, qn_b, kn_w, kn_b);
  vtrans<<<512, 256, 0, stream>>>(qkv + 8388608, vtw);
  attn_kernel<<<1024, 256, 0, stream>>>(qkv, qkv + 4194304, vtw, sinks, ao);
  gemm128<1><<<dim3(8, 32), 256, 0, stream>>>(ao, proj_w, out, proj_b, 1024);
}

// Round 3
// 218.848 us; speedup vs baseline: 1.0365x; 1.0365x over previous
//
#include <hip/hip_runtime.h>
#include <stdint.h>

typedef unsigned short u16;
typedef __bf16 bf16x8 __attribute__((ext_vector_type(8)));
typedef float f32x4 __attribute__((ext_vector_type(4)));

__device__ __forceinline__ float b2f(u16 u) {
  union { uint32_t i; float f; } x; x.i = ((uint32_t)u) << 16; return x.f;
}
__device__ __forceinline__ u16 f2b(float f) {
  union { float f; uint32_t i; } x; x.f = f;
  uint32_t r = x.i + 0x7fffu + ((x.i >> 16) & 1u);
  return (u16)(r >> 16);
}
// async global->LDS, 16B per lane, LDS dest = wave-uniform base + lane*16
__device__ __forceinline__ void gload_lds16(const u16* g, u16* l) {
  __builtin_amdgcn_global_load_lds(
      (const __attribute__((address_space(1))) void*)g,
      (__attribute__((address_space(3))) void*)l, 16, 0, 0);
}

// ---------------------------------------------------------------------------
// fp32 -> bf16 prepass: x (4194304) | qkv_w (3145728) | proj_w (1048576)
// into one flat bf16 region. 8192 blocks x 256 thr x 4 elems.
// ---------------------------------------------------------------------------
__launch_bounds__(256)
__global__ void cvt_bf16(const float* __restrict__ x, const float* __restrict__ wq,
                         const float* __restrict__ wp, u16* __restrict__ dst) {
  const int i = (blockIdx.x * 256 + threadIdx.x) * 4;
  const float* src; int off;
  if (i < 4194304)      { src = x;  off = i; }
  else if (i < 7340032) { src = wq; off = i - 4194304; }
  else                  { src = wp; off = i - 7340032; }
  const float4 v = *(const float4*)(src + off);
  ushort4 o;
  o.x = f2b(v.x); o.y = f2b(v.y); o.z = f2b(v.z); o.w = f2b(v.w);
  *(ushort4*)(dst + i) = o;
}

// ---------------------------------------------------------------------------
// RoPE cos/sin table: tab[pos*64+d] = {cos, sin} of pos * 10000^-((d&31)/32)
// ---------------------------------------------------------------------------
__launch_bounds__(256)
__global__ void rope_tab(float* __restrict__ tab) {
  const int tid = blockIdx.x * 256 + threadIdx.x;   // 65536
  const int pos = tid >> 6, d = tid & 63, i = d & 31;
  const float f = pos * exp2f(i * -0.41524101186092029f); // -log2(10000)/32
  float s, c;
  sincosf(f, &s, &c);
  *(float2*)(tab + tid * 2) = make_float2(c, s);
}

// ---------------------------------------------------------------------------
// GEMM: C[m,n] = sum_k A[m,k] * B[n,k]  (bf16, row-major, K contiguous)
// m97 structure: 128x128 tile, BK=32, 4 waves (2x2 of 64x64), staging via
// global_load_lds width=16 (2 insts/side/thread), 2-barrier K-loop.
// MODE 0: scatter bf16 into qkv ws layout [3][B][H][N][D]
// MODE 1: fp32 out + fp32 bias
// ---------------------------------------------------------------------------
template<int MODE>
__launch_bounds__(256)
__global__ void gemm128(const u16* __restrict__ A, const u16* __restrict__ Bw,
                        void* __restrict__ Cp, const float* __restrict__ bias, int K) {
  __shared__ __align__(16) u16 As[128 * 32];
  __shared__ __align__(16) u16 Bs[128 * 32];
  const int t = threadIdx.x;
  const int w = t >> 6, l = t & 63, lr = l & 15, lg = l >> 4;
  const int m0 = blockIdx.y * 128, n0 = blockIdx.x * 128;
  const int wm = (w >> 1) * 64, wn = (w & 1) * 64;
  // staging: wave w owns rows [w*32, w*32+32); inst covers 16 rows (64 lanes x 16B)
  const int srow = w * 32 + (l >> 2);
  const int scol = (l & 3) * 8;
  const u16* ga0 = A  + (m0 + srow) * K + scol;
  const u16* ga1 = ga0 + 16 * K;
  const u16* gb0 = Bw + (n0 + srow) * K + scol;
  const u16* gb1 = gb0 + 16 * K;
  u16* la0 = As + w * 1024;        // wave-uniform LDS bases (u16 elems)
  u16* la1 = As + w * 1024 + 512;
  u16* lb0 = Bs + w * 1024;
  u16* lb1 = Bs + w * 1024 + 512;

  f32x4 acc[4][4] = {};
  const int nk = K >> 5;
  for (int kt = 0; kt < nk; ++kt) {
    const int ko = kt * 32;
    __syncthreads();
    gload_lds16(ga0 + ko, la0);
    gload_lds16(ga1 + ko, la1);
    gload_lds16(gb0 + ko, lb0);
    gload_lds16(gb1 + ko, lb1);
    __syncthreads();
    bf16x8 af[4], bfr[4];
#pragma unroll
    for (int i = 0; i < 4; ++i)
      af[i] = *(const bf16x8*)(As + (wm + i * 16 + lr) * 32 + lg * 8);
#pragma unroll
    for (int j = 0; j < 4; ++j)
      bfr[j] = *(const bf16x8*)(Bs + (wn + j * 16 + lr) * 32 + lg * 8);
#pragma unroll
    for (int i = 0; i < 4; ++i)
#pragma unroll
      for (int j = 0; j < 4; ++j)
        acc[i][j] = __builtin_amdgcn_mfma_f32_16x16x32_bf16(af[i], bfr[j], acc[i][j], 0, 0, 0);
  }
  // epilogue: C/D layout col=lane&15, row=(lane>>4)*4+reg
#pragma unroll
  for (int i = 0; i < 4; ++i)
#pragma unroll
    for (int j = 0; j < 4; ++j)
#pragma unroll
      for (int r = 0; r < 4; ++r) {
        const int gm = m0 + wm + i * 16 + lg * 4 + r;
        const int gn = n0 + wn + j * 16 + lr;
        const float v = acc[i][j][r];
        if (MODE == 0) {
          const int which = gn >> 10, hh = (gn >> 6) & 15, dd = gn & 63;
          const int bb = gm >> 10, pp = gm & 1023;
          ((u16*)Cp)[which * 4194304 + ((bb * 16 + hh) << 16) + (pp << 6) + dd] = f2b(v);
        } else {
          ((float*)Cp)[(gm << 10) + gn] = v + bias[gn];
        }
      }
}

// ---------------------------------------------------------------------------
// LayerNorm(D=64) + RoPE over q and k regions (131072 rows of 64), in place
// on bf16 ws. One wave = 2 rows: 32 lanes/row, 2 elems/lane. cos/sin from tab.
// ---------------------------------------------------------------------------
__launch_bounds__(256)
__global__ void ln_rope(u16* __restrict__ qk, const float* __restrict__ qn_w,
                        const float* __restrict__ qn_b, const float* __restrict__ kn_w,
                        const float* __restrict__ kn_b, const float* __restrict__ tab) {
  const int t = threadIdx.x;
  const int wid = blockIdx.x * 4 + (t >> 6);
  const int l = t & 63;
  const int row = wid * 2 + (l >> 5);
  const int j = l & 31, d0 = j * 2;
  const int which = row >> 16;   // 65536 rows per q/k region
  const int pos = row & 1023;
  const float* wgt = which ? kn_w : qn_w;
  const float* bia = which ? kn_b : qn_b;
  u16* p = qk + row * 64 + d0;
  const ushort2 raw = *(const ushort2*)p;
  float v0 = b2f(raw.x), v1 = b2f(raw.y);
  float s = v0 + v1;
#pragma unroll
  for (int off = 1; off < 32; off <<= 1) s += __shfl_xor(s, off);
  const float mu = s * 0.015625f;
  const float e0 = v0 - mu, e1 = v1 - mu;
  float qsum = e0 * e0 + e1 * e1;
#pragma unroll
  for (int off = 1; off < 32; off <<= 1) qsum += __shfl_xor(qsum, off);
  const float rstd = rsqrtf(qsum * 0.015625f + 1e-5f);
  const float n0 = e0 * rstd * wgt[d0] + bia[d0];
  const float n1 = e1 * rstd * wgt[d0 + 1] + bia[d0 + 1];
  // rotate_half partner lives at d ^ 32 -> lane ^ 16 within the 32-lane half
  const float p0 = __shfl_xor(n0, 16);
  const float p1 = __shfl_xor(n1, 16);
  const bool lo = (d0 < 32);
  const float r0 = lo ? -p0 : p0, r1 = lo ? -p1 : p1;
  const float4 cs = *(const float4*)(tab + (pos * 64 + d0) * 2); // {c0,s0,c1,s1}
  ushort2 o;
  o.x = f2b(n0 * cs.x + r0 * cs.y);
  o.y = f2b(n1 * cs.z + r1 * cs.w);
  *(ushort2*)p = o;
}

// ---------------------------------------------------------------------------
// V transpose: [B,H,N,D] -> [B,H,D,N] via 128x64 LDS tile (bf16 ws).
// ---------------------------------------------------------------------------
__launch_bounds__(256)
__global__ void vtrans(const u16* __restrict__ v, u16* __restrict__ vt) {
  __shared__ u16 tile[128 * 65];
  const int t = threadIdx.x;
  const int bh = blockIdx.x >> 3;
  const int n0 = (blockIdx.x & 7) * 128;
  const u16* src = v + bh * 65536 + n0 * 64;
#pragma unroll
  for (int it = 0; it < 8; ++it) {
    const int e = (it * 256 + t) * 4;
    const int n = e >> 6, d = e & 63;
    const ushort4 x = *(const ushort4*)(src + n * 64 + d);
    tile[n * 65 + d + 0] = x.x;
    tile[n * 65 + d + 1] = x.y;
    tile[n * 65 + d + 2] = x.z;
    tile[n * 65 + d + 3] = x.w;
  }
  __syncthreads();
  u16* dst = vt + bh * 65536 + n0;
#pragma unroll
  for (int it = 0; it < 8; ++it) {
    const int o = (it * 256 + t) * 4;
    const int d = o >> 7, c = o & 127;
    ushort4 y;
    y.x = tile[(c + 0) * 65 + d];
    y.y = tile[(c + 1) * 65 + d];
    y.z = tile[(c + 2) * 65 + d];
    y.w = tile[(c + 3) * 65 + d];
    *(ushort4*)(dst + d * 1024 + c) = y;
  }
}

// ---------------------------------------------------------------------------
// Sliding-window attention with sinks. One wave per 16 q-rows.
// QK^T: 17 coltiles of 16 keys in registers (C-layout), register softmax,
// P -> LDS (A-layout transform), PV: 9 K-steps x 4 d-tiles, V^T from global.
// ---------------------------------------------------------------------------
__launch_bounds__(256)
__global__ void attn_kernel(const u16* __restrict__ q, const u16* __restrict__ k,
                            const u16* __restrict__ vt, const float* __restrict__ sinks,
                            u16* __restrict__ ao) {
  __shared__ __align__(16) u16 pbuf[4][16 * 296];
  const int t = threadIdx.x, w = t >> 6, l = t & 63, lr = l & 15, lg = l >> 4;
  const int bid = blockIdx.x;
  const int qb = bid & 15, h = (bid >> 4) & 15, b = bid >> 8;
  const int i0 = qb * 64 + w * 16;
  const int bh = b * 16 + h;
  const u16* qp = q + bh * 65536;
  const u16* kp = k + bh * 65536;
  const u16* vp = vt + bh * 65536;
  u16* pb = pbuf[w];

  const bf16x8 qf0 = *(const bf16x8*)(qp + (i0 + lr) * 64 + lg * 8);
  const bf16x8 qf1 = *(const bf16x8*)(qp + (i0 + lr) * 64 + 32 + lg * 8);
  const int ja = i0 - 256;

  f32x4 sacc[17];
#pragma unroll
  for (int jt = 0; jt < 17; ++jt) {
    const int jr = ja + jt * 16 + lr;
    const int jc = jr < 0 ? 0 : jr;
    const bf16x8 kf0 = *(const bf16x8*)(kp + jc * 64 + lg * 8);
    const bf16x8 kf1 = *(const bf16x8*)(kp + jc * 64 + 32 + lg * 8);
    f32x4 a = {0.f, 0.f, 0.f, 0.f};
    a = __builtin_amdgcn_mfma_f32_16x16x32_bf16(qf0, kf0, a, 0, 0, 0);
    a = __builtin_amdgcn_mfma_f32_16x16x32_bf16(qf1, kf1, a, 0, 0, 0);
    sacc[jt] = a;
  }
  const float sink = sinks[h];
  float mx[4] = {-1e30f, -1e30f, -1e30f, -1e30f};
#pragma unroll
  for (int jt = 0; jt < 17; ++jt)
#pragma unroll
    for (int r = 0; r < 4; ++r) {
      const int qi = i0 + lg * 4 + r;
      const int jg = ja + jt * 16 + lr;
      const bool ok = (jg >= 0) && (jg <= qi) && (jg > qi - 256);
      const float sv = ok ? sacc[jt][r] * 0.125f : -1e30f;
      sacc[jt][r] = sv;
      mx[r] = fmaxf(mx[r], sv);
    }
#pragma unroll
  for (int off = 1; off < 16; off <<= 1)
#pragma unroll
    for (int r = 0; r < 4; ++r) mx[r] = fmaxf(mx[r], __shfl_xor(mx[r], off));
#pragma unroll
  for (int r = 0; r < 4; ++r) mx[r] = fmaxf(mx[r], sink);
  float sum[4] = {0.f, 0.f, 0.f, 0.f};
#pragma unroll
  for (int jt = 0; jt < 17; ++jt)
#pragma unroll
    for (int r = 0; r < 4; ++r) {
      const float e = __expf(sacc[jt][r] - mx[r]);
      sacc[jt][r] = e;
      sum[r] += e;
    }
#pragma unroll
  for (int off = 1; off < 16; off <<= 1)
#pragma unroll
    for (int r = 0; r < 4; ++r) sum[r] += __shfl_xor(sum[r], off);
  float inv[4];
#pragma unroll
  for (int r = 0; r < 4; ++r) inv[r] = 1.0f / (sum[r] + __expf(sink - mx[r]));
  // zero pad cols [272,288) so the 9th PV K-step contributes nothing
  {
    ushort4 z; z.x = 0; z.y = 0; z.z = 0; z.w = 0;
    *(ushort4*)(pb + (l >> 2) * 296 + 272 + (l & 3) * 4) = z;
  }
#pragma unroll
  for (int jt = 0; jt < 17; ++jt)
#pragma unroll
    for (int r = 0; r < 4; ++r)
      pb[(lg * 4 + r) * 296 + jt * 16 + lr] = f2b(sacc[jt][r] * inv[r]);

  f32x4 oacc[4] = {};
#pragma unroll
  for (int ks = 0; ks < 9; ++ks) {
    const bf16x8 pf = *(const bf16x8*)(pb + lr * 296 + ks * 32 + lg * 8);
#pragma unroll
    for (int dt = 0; dt < 4; ++dt) {
      int jg = ja + ks * 32 + lg * 8;
      jg = jg < 0 ? 0 : (jg > 1016 ? 1016 : jg);
      const bf16x8 vf = *(const bf16x8*)(vp + (dt * 16 + lr) * 1024 + jg);
      oacc[dt] = __builtin_amdgcn_mfma_f32_16x16x32_bf16(pf, vf, oacc[dt], 0, 0, 0);
    }
  }
#pragma unroll
  for (int dt = 0; dt < 4; ++dt)
#pragma unroll
    for (int r = 0; r < 4; ++r) {
      const int m = (b << 10) + i0 + lg * 4 + r;
      ao[(m << 10) + (h << 6) + dt * 16 + lr] = f2b(oacc[dt][r]);
    }
}

// ---------------------------------------------------------------------------
// ws layout (u16 elems):
//   qkv     @ 0         (12582912)  q/k/v [3][B][H][N][D]
//   xb      @ 12582912  (4194304)   x bf16      -- dead after qkv gemm
//   wqkvb   @ 16777216  (3145728)   qkv_w bf16  -- dead after qkv gemm
//   wprojb  @ 19922944  (1048576)   proj_w bf16
//   ropetab @ 20971520  (262144 u16 = 131072 f32)
//   ao      @ 21233664  (4194304)
//   vt      @ 12582912  -- aliases dead xb
// total 50,855,936 bytes
// ---------------------------------------------------------------------------
extern "C" void kernel_launch(void* const* d_in, const int* in_sizes, int n_in,
                              void* d_out, int out_size, void* d_ws, size_t ws_size,
                              hipStream_t stream) {
  const float* x      = (const float*)d_in[0];
  const float* qkv_w  = (const float*)d_in[1];
  const float* qn_w   = (const float*)d_in[2];
  const float* qn_b   = (const float*)d_in[3];
  const float* kn_w   = (const float*)d_in[4];
  const float* kn_b   = (const float*)d_in[5];
  const float* sinks  = (const float*)d_in[6];
  const float* proj_w = (const float*)d_in[7];
  const float* proj_b = (const float*)d_in[8];
  float* out = (float*)d_out;
  u16* ws     = (u16*)d_ws;
  u16* qkv    = ws;
  u16* xb     = ws + 12582912;
  u16* wqkvb  = ws + 16777216;
  u16* wprojb = ws + 19922944;
  float* tab  = (float*)(ws + 20971520);
  u16* ao     = ws + 21233664;
  u16* vtw    = ws + 12582912;   // aliases xb (dead after qkv gemm)

  cvt_bf16<<<8192, 256, 0, stream>>>(x, qkv_w, proj_w, xb);
  rope_tab<<<256, 256, 0, stream>>>(tab);
  gemm128<0><<<dim3(24, 32), 256, 0, stream>>>(xb, wqkvb, qkv, nullptr, 1024);
  ln_rope<<<16384, 256, 0, stream>>>(qkv, qn_w, qn_b, kn_w, kn_b, tab);
  vtrans<<<512, 256, 0, stream>>>(qkv + 8388608, vtw);
  attn_kernel<<<1024, 256, 0, stream>>>(qkv, qkv + 4194304, vtw, sinks, ao);
  gemm128<1><<<dim3(8, 32), 256, 0, stream>>>(ao, wprojb, out, proj_b, 1024);
}

// Round 4
// 199.349 us; speedup vs baseline: 1.1379x; 1.0978x over previous
//
#include <hip/hip_runtime.h>
#include <stdint.h>

typedef unsigned short u16;
typedef __bf16 bf16x8 __attribute__((ext_vector_type(8)));
typedef float f32x4 __attribute__((ext_vector_type(4)));

__device__ __forceinline__ float b2f(u16 u) {
  union { uint32_t i; float f; } x; x.i = ((uint32_t)u) << 16; return x.f;
}
__device__ __forceinline__ u16 f2b(float f) {
  union { float f; uint32_t i; } x; x.f = f;
  uint32_t r = x.i + 0x7fffu + ((x.i >> 16) & 1u);
  return (u16)(r >> 16);
}
// async global->LDS, 16B per lane, LDS dest = wave-uniform base + lane*16
__device__ __forceinline__ void gload_lds16(const u16* g, u16* l) {
  __builtin_amdgcn_global_load_lds(
      (const __attribute__((address_space(1))) void*)g,
      (__attribute__((address_space(3))) void*)l, 16, 0, 0);
}

// ---------------------------------------------------------------------------
// fp32 -> bf16 prepass: x (4194304) | qkv_w (3145728) | proj_w (1048576)
// ---------------------------------------------------------------------------
__launch_bounds__(256)
__global__ void cvt_bf16(const float* __restrict__ x, const float* __restrict__ wq,
                         const float* __restrict__ wp, u16* __restrict__ dst) {
  const int i = (blockIdx.x * 256 + threadIdx.x) * 4;
  const float* src; int off;
  if (i < 4194304)      { src = x;  off = i; }
  else if (i < 7340032) { src = wq; off = i - 4194304; }
  else                  { src = wp; off = i - 7340032; }
  const float4 v = *(const float4*)(src + off);
  ushort4 o;
  o.x = f2b(v.x); o.y = f2b(v.y); o.z = f2b(v.z); o.w = f2b(v.w);
  *(ushort4*)(dst + i) = o;
}

// ---------------------------------------------------------------------------
// RoPE cos/sin table: tab[(pos*64+d)*2] = {cos, sin}
// ---------------------------------------------------------------------------
__launch_bounds__(256)
__global__ void rope_tab(float* __restrict__ tab) {
  const int tid = blockIdx.x * 256 + threadIdx.x;   // 65536
  const int pos = tid >> 6, d = tid & 63, i = d & 31;
  const float f = pos * exp2f(i * -0.41524101186092029f); // -log2(10000)/32
  float s, c;
  sincosf(f, &s, &c);
  *(float2*)(tab + tid * 2) = make_float2(c, s);
}

// ---------------------------------------------------------------------------
// GEMM (m97 structure), unchanged from round 3.
// ---------------------------------------------------------------------------
template<int MODE>
__launch_bounds__(256)
__global__ void gemm128(const u16* __restrict__ A, const u16* __restrict__ Bw,
                        void* __restrict__ Cp, const float* __restrict__ bias, int K) {
  __shared__ __align__(16) u16 As[128 * 32];
  __shared__ __align__(16) u16 Bs[128 * 32];
  const int t = threadIdx.x;
  const int w = t >> 6, l = t & 63, lr = l & 15, lg = l >> 4;
  const int m0 = blockIdx.y * 128, n0 = blockIdx.x * 128;
  const int wm = (w >> 1) * 64, wn = (w & 1) * 64;
  const int srow = w * 32 + (l >> 2);
  const int scol = (l & 3) * 8;
  const u16* ga0 = A  + (m0 + srow) * K + scol;
  const u16* ga1 = ga0 + 16 * K;
  const u16* gb0 = Bw + (n0 + srow) * K + scol;
  const u16* gb1 = gb0 + 16 * K;
  u16* la0 = As + w * 1024;
  u16* la1 = As + w * 1024 + 512;
  u16* lb0 = Bs + w * 1024;
  u16* lb1 = Bs + w * 1024 + 512;

  f32x4 acc[4][4] = {};
  const int nk = K >> 5;
  for (int kt = 0; kt < nk; ++kt) {
    const int ko = kt * 32;
    __syncthreads();
    gload_lds16(ga0 + ko, la0);
    gload_lds16(ga1 + ko, la1);
    gload_lds16(gb0 + ko, lb0);
    gload_lds16(gb1 + ko, lb1);
    __syncthreads();
    bf16x8 af[4], bfr[4];
#pragma unroll
    for (int i = 0; i < 4; ++i)
      af[i] = *(const bf16x8*)(As + (wm + i * 16 + lr) * 32 + lg * 8);
#pragma unroll
    for (int j = 0; j < 4; ++j)
      bfr[j] = *(const bf16x8*)(Bs + (wn + j * 16 + lr) * 32 + lg * 8);
#pragma unroll
    for (int i = 0; i < 4; ++i)
#pragma unroll
      for (int j = 0; j < 4; ++j)
        acc[i][j] = __builtin_amdgcn_mfma_f32_16x16x32_bf16(af[i], bfr[j], acc[i][j], 0, 0, 0);
  }
#pragma unroll
  for (int i = 0; i < 4; ++i)
#pragma unroll
    for (int j = 0; j < 4; ++j)
#pragma unroll
      for (int r = 0; r < 4; ++r) {
        const int gm = m0 + wm + i * 16 + lg * 4 + r;
        const int gn = n0 + wn + j * 16 + lr;
        const float v = acc[i][j][r];
        if (MODE == 0) {
          const int which = gn >> 10, hh = (gn >> 6) & 15, dd = gn & 63;
          const int bb = gm >> 10, pp = gm & 1023;
          ((u16*)Cp)[which * 4194304 + ((bb * 16 + hh) << 16) + (pp << 6) + dd] = f2b(v);
        } else {
          ((float*)Cp)[(gm << 10) + gn] = v + bias[gn];
        }
      }
}

// ---------------------------------------------------------------------------
// LayerNorm(D=64) + RoPE, 8 rows/wave, 8 lanes/row, 8 elems/lane, in place.
// K region is written CHUNK-PERMUTED: 16B chunk c of row pos -> slot c^(pos&7)
// (bank-conflict-free LDS image after linear global_load_lds staging in attn).
// ---------------------------------------------------------------------------
__launch_bounds__(256)
__global__ void ln_rope(u16* __restrict__ qk, const float* __restrict__ qn_w,
                        const float* __restrict__ qn_b, const float* __restrict__ kn_w,
                        const float* __restrict__ kn_b, const float* __restrict__ tab) {
  const int t = threadIdx.x, l = t & 63;
  const int wv = blockIdx.x * 4 + (t >> 6);
  const int row = wv * 8 + (l >> 3);     // 0..131071
  const int c = l & 7;                   // 8-elem chunk index
  const int which = row >> 16;           // 0 = q, 1 = k
  const int pos = row & 1023;
  const float* wgt = which ? kn_w : qn_w;
  const float* bia = which ? kn_b : qn_b;
  const u16* src = qk + row * 64 + c * 8;
  const ushort4 ra = *(const ushort4*)(src);
  const ushort4 rb = *(const ushort4*)(src + 4);
  float v[8] = {b2f(ra.x), b2f(ra.y), b2f(ra.z), b2f(ra.w),
                b2f(rb.x), b2f(rb.y), b2f(rb.z), b2f(rb.w)};
  float s = 0.f;
#pragma unroll
  for (int i = 0; i < 8; ++i) s += v[i];
#pragma unroll
  for (int off = 1; off < 8; off <<= 1) s += __shfl_xor(s, off);
  const float mu = s * 0.015625f;
  float e[8], qs = 0.f;
#pragma unroll
  for (int i = 0; i < 8; ++i) { e[i] = v[i] - mu; qs += e[i] * e[i]; }
#pragma unroll
  for (int off = 1; off < 8; off <<= 1) qs += __shfl_xor(qs, off);
  const float rstd = rsqrtf(qs * 0.015625f + 1e-5f);
  const int d0 = c * 8;
  float wb[8], bb[8];
  *(float4*)(wb) = *(const float4*)(wgt + d0);
  *(float4*)(wb + 4) = *(const float4*)(wgt + d0 + 4);
  *(float4*)(bb) = *(const float4*)(bia + d0);
  *(float4*)(bb + 4) = *(const float4*)(bia + d0 + 4);
  float n[8], r[8];
#pragma unroll
  for (int i = 0; i < 8; ++i) n[i] = e[i] * rstd * wb[i] + bb[i];
  // rotate_half partner: d^32 -> lane c^4
#pragma unroll
  for (int i = 0; i < 8; ++i) r[i] = __shfl_xor(n[i], 4);
  const bool lo = (c < 4);
#pragma unroll
  for (int i = 0; i < 8; ++i) r[i] = lo ? -r[i] : r[i];
  float cs[16];
  *(float4*)(cs)      = *(const float4*)(tab + (pos * 64 + d0) * 2);
  *(float4*)(cs + 4)  = *(const float4*)(tab + (pos * 64 + d0) * 2 + 4);
  *(float4*)(cs + 8)  = *(const float4*)(tab + (pos * 64 + d0) * 2 + 8);
  *(float4*)(cs + 12) = *(const float4*)(tab + (pos * 64 + d0) * 2 + 12);
  ushort4 oa, ob;
  float o[8];
#pragma unroll
  for (int i = 0; i < 8; ++i) o[i] = n[i] * cs[2 * i] + r[i] * cs[2 * i + 1];
  oa.x = f2b(o[0]); oa.y = f2b(o[1]); oa.z = f2b(o[2]); oa.w = f2b(o[3]);
  ob.x = f2b(o[4]); ob.y = f2b(o[5]); ob.z = f2b(o[6]); ob.w = f2b(o[7]);
  const int dstc = which ? (c ^ (pos & 7)) : c;   // permute K only
  u16* dst = qk + row * 64 + dstc * 8;
  *(ushort4*)(dst) = oa;
  *(ushort4*)(dst + 4) = ob;
}

// ---------------------------------------------------------------------------
// V transpose: [B,H,N,D] -> chunked [B,H,nblk=16][D=64][64], with 16B chunk
// (jl>>3) of row d stored at slot (jl>>3)^(d&7) (same swizzle scheme).
// ---------------------------------------------------------------------------
__launch_bounds__(256)
__global__ void vtrans(const u16* __restrict__ v, u16* __restrict__ vt) {
  __shared__ u16 tile[128 * 65];
  const int t = threadIdx.x;
  const int bh = blockIdx.x >> 3;
  const int n0 = (blockIdx.x & 7) * 128;
  const u16* src = v + bh * 65536 + n0 * 64;
#pragma unroll
  for (int it = 0; it < 8; ++it) {
    const int e = (it * 256 + t) * 4;
    const int n = e >> 6, d = e & 63;
    const ushort4 x = *(const ushort4*)(src + n * 64 + d);
    tile[n * 65 + d + 0] = x.x;
    tile[n * 65 + d + 1] = x.y;
    tile[n * 65 + d + 2] = x.z;
    tile[n * 65 + d + 3] = x.w;
  }
  __syncthreads();
  u16* dst = vt + bh * 65536;
#pragma unroll
  for (int it = 0; it < 8; ++it) {
    const int o = (it * 256 + t) * 4;
    const int d = o >> 7, c = o & 127;
    ushort4 y;
    y.x = tile[(c + 0) * 65 + d];
    y.y = tile[(c + 1) * 65 + d];
    y.z = tile[(c + 2) * 65 + d];
    y.w = tile[(c + 3) * 65 + d];
    const int gj = n0 + c;
    const int nb = gj >> 6, jl = gj & 63;
    const int slot = (jl >> 3) ^ (d & 7);
    *(ushort4*)(dst + nb * 4096 + d * 64 + slot * 8 + (jl & 7)) = y;
  }
}

// ---------------------------------------------------------------------------
// Sliding-window attention with sinks. Block = 64 q-rows of one (b,h);
// waves w=0..3 take 16 rows each. K tile (320 rows, contiguous 40KB) and
// V tile (5 x 8KB chunks) staged into LDS via async global_load_lds burst
// (sources pre-swizzled by ln_rope / vtrans -> conflict-free LDS reads).
// P-buffer aliases Ks after a barrier. LDS total = 81920 B -> 2 blocks/CU.
// ---------------------------------------------------------------------------
__launch_bounds__(256, 2)
__global__ void attn_kernel(const u16* __restrict__ q, const u16* __restrict__ k,
                            const u16* __restrict__ vt, const float* __restrict__ sinks,
                            u16* __restrict__ ao) {
  __shared__ __align__(16) u16 Ks[20480];   // 320 rows x 64 (40960 B)
  __shared__ __align__(16) u16 Vs[20480];   // 5 chunks x [64][64] (40960 B)
  const int t = threadIdx.x, w = t >> 6, l = t & 63, lr = l & 15, lg = l >> 4;
  const int bid = blockIdx.x;
  const int qb = bid & 15, h = (bid >> 4) & 15, b = bid >> 8;
  const int i0 = qb * 64 + w * 16;
  const int bh = b * 16 + h;
  const u16* qp = q + bh * 65536;
  const u16* kp = k + bh * 65536;
  const u16* vp = vt + bh * 65536;
  const int j0 = qb * 64 - 256;

  // --- async staging burst: 10 K-chunks + 10 V-chunks per wave (1KB each)
#pragma unroll
  for (int i = 0; i < 10; ++i) {
    const int c = w * 10 + i;
    int off = j0 * 64 + c * 512 + l * 8;
    off = off < 0 ? 0 : off;
    gload_lds16(kp + off, Ks + c * 512);
  }
#pragma unroll
  for (int i = 0; i < 10; ++i) {
    const int c = w * 10 + i;
    const int n = c >> 3, p = c & 7;
    int nb = qb - 4 + n;
    nb = nb < 0 ? 0 : nb;
    gload_lds16(vp + nb * 4096 + p * 512 + l * 8, Vs + c * 512);
  }
  // Q frags direct from global (unpermuted region)
  const bf16x8 qf0 = *(const bf16x8*)(qp + (i0 + lr) * 64 + lg * 8);
  const bf16x8 qf1 = *(const bf16x8*)(qp + (i0 + lr) * 64 + 32 + lg * 8);
  __syncthreads();

  // --- QK^T from LDS (swizzled chunk addressing)
  const int key = lr & 7;
  f32x4 sacc[17];
#pragma unroll
  for (int jt = 0; jt < 17; ++jt) {
    const int r = w * 16 + jt * 16 + lr;          // LDS row
    const bf16x8 kf0 = *(const bf16x8*)(Ks + r * 64 + ((lg ^ key)) * 8);
    const bf16x8 kf1 = *(const bf16x8*)(Ks + r * 64 + (((lg + 4) ^ key)) * 8);
    f32x4 a = {0.f, 0.f, 0.f, 0.f};
    a = __builtin_amdgcn_mfma_f32_16x16x32_bf16(qf0, kf0, a, 0, 0, 0);
    a = __builtin_amdgcn_mfma_f32_16x16x32_bf16(qf1, kf1, a, 0, 0, 0);
    sacc[jt] = a;
  }
  const float sink = sinks[h];
  const int ja = i0 - 256;
  float mx[4] = {-1e30f, -1e30f, -1e30f, -1e30f};
#pragma unroll
  for (int jt = 0; jt < 17; ++jt)
#pragma unroll
    for (int r = 0; r < 4; ++r) {
      const int qi = i0 + lg * 4 + r;
      const int jg = ja + jt * 16 + lr;
      const bool ok = (jg >= 0) && (jg <= qi) && (jg > qi - 256);
      const float sv = ok ? sacc[jt][r] * 0.125f : -1e30f;
      sacc[jt][r] = sv;
      mx[r] = fmaxf(mx[r], sv);
    }
#pragma unroll
  for (int off = 1; off < 16; off <<= 1)
#pragma unroll
    for (int r = 0; r < 4; ++r) mx[r] = fmaxf(mx[r], __shfl_xor(mx[r], off));
#pragma unroll
  for (int r = 0; r < 4; ++r) mx[r] = fmaxf(mx[r], sink);
  float sum[4] = {0.f, 0.f, 0.f, 0.f};
#pragma unroll
  for (int jt = 0; jt < 17; ++jt)
#pragma unroll
    for (int r = 0; r < 4; ++r) {
      const float e = __expf(sacc[jt][r] - mx[r]);
      sacc[jt][r] = e;
      sum[r] += e;
    }
#pragma unroll
  for (int off = 1; off < 16; off <<= 1)
#pragma unroll
    for (int r = 0; r < 4; ++r) sum[r] += __shfl_xor(sum[r], off);
  float inv[4];
#pragma unroll
  for (int r = 0; r < 4; ++r) inv[r] = 1.0f / (sum[r] + __expf(sink - mx[r]));

  __syncthreads();                 // everyone done reading Ks -> reuse as pbuf
  u16* pb = Ks + w * 4736;         // 16 rows x stride 296
  {
    ushort4 z; z.x = 0; z.y = 0; z.z = 0; z.w = 0;
    *(ushort4*)(pb + (l >> 2) * 296 + 272 + (l & 3) * 4) = z;
  }
#pragma unroll
  for (int jt = 0; jt < 17; ++jt)
#pragma unroll
    for (int r = 0; r < 4; ++r)
      pb[(lg * 4 + r) * 296 + jt * 16 + lr] = f2b(sacc[jt][r] * inv[r]);

  // --- PV from LDS
  f32x4 oacc[4] = {};
#pragma unroll
  for (int ks = 0; ks < 9; ++ks) {
    const bf16x8 pf = *(const bf16x8*)(pb + lr * 296 + ks * 32 + lg * 8);
#pragma unroll
    for (int dt = 0; dt < 4; ++dt) {
      int r = w * 16 + ks * 32 + lg * 8;
      r = r < 320 ? r : 0;                        // P=0 columns -> any valid V
      const int n = r >> 6, jl = r & 63;
      const int slot = (jl >> 3) ^ (lr & 7);
      const bf16x8 vf = *(const bf16x8*)(Vs + n * 4096 + (dt * 16 + lr) * 64 + slot * 8);
      oacc[dt] = __builtin_amdgcn_mfma_f32_16x16x32_bf16(pf, vf, oacc[dt], 0, 0, 0);
    }
  }
#pragma unroll
  for (int dt = 0; dt < 4; ++dt)
#pragma unroll
    for (int r = 0; r < 4; ++r) {
      const int m = (b << 10) + i0 + lg * 4 + r;
      ao[(m << 10) + (h << 6) + dt * 16 + lr] = f2b(oacc[dt][r]);
    }
}

// ---------------------------------------------------------------------------
// ws layout (u16 elems):
//   qkv     @ 0         (12582912)  q/k/v [3][B][H][N][D] (k chunk-permuted)
//   xb      @ 12582912  (4194304)   x bf16      -- dead after qkv gemm
//   wqkvb   @ 16777216  (3145728)   qkv_w bf16  -- dead after qkv gemm
//   wprojb  @ 19922944  (1048576)   proj_w bf16
//   ropetab @ 20971520  (262144 u16 = 131072 f32)
//   ao      @ 21233664  (4194304)
//   vt      @ 12582912  -- aliases dead xb (chunked+swizzled layout)
// ---------------------------------------------------------------------------
extern "C" void kernel_launch(void* const* d_in, const int* in_sizes, int n_in,
                              void* d_out, int out_size, void* d_ws, size_t ws_size,
                              hipStream_t stream) {
  const float* x      = (const float*)d_in[0];
  const float* qkv_w  = (const float*)d_in[1];
  const float* qn_w   = (const float*)d_in[2];
  const float* qn_b   = (const float*)d_in[3];
  const float* kn_w   = (const float*)d_in[4];
  const float* kn_b   = (const float*)d_in[5];
  const float* sinks  = (const float*)d_in[6];
  const float* proj_w = (const float*)d_in[7];
  const float* proj_b = (const float*)d_in[8];
  float* out = (float*)d_out;
  u16* ws     = (u16*)d_ws;
  u16* qkv    = ws;
  u16* xb     = ws + 12582912;
  u16* wqkvb  = ws + 16777216;
  u16* wprojb = ws + 19922944;
  float* tab  = (float*)(ws + 20971520);
  u16* ao     = ws + 21233664;
  u16* vtw    = ws + 12582912;   // aliases xb (dead after qkv gemm)

  cvt_bf16<<<8192, 256, 0, stream>>>(x, qkv_w, proj_w, xb);
  rope_tab<<<256, 256, 0, stream>>>(tab);
  gemm128<0><<<dim3(24, 32), 256, 0, stream>>>(xb, wqkvb, qkv, nullptr, 1024);
  ln_rope<<<4096, 256, 0, stream>>>(qkv, qn_w, qn_b, kn_w, kn_b, tab);
  vtrans<<<512, 256, 0, stream>>>(qkv + 8388608, vtw);
  attn_kernel<<<1024, 256, 0, stream>>>(qkv, qkv + 4194304, vtw, sinks, ao);
  gemm128<1><<<dim3(8, 32), 256, 0, stream>>>(ao, wprojb, out, proj_b, 1024);
}